// Round 4
// baseline (6756.982 us; speedup 1.0000x reference)
//
#include <hip/hip_runtime.h>
#include <hip/hip_bf16.h>

// Neural CDE forward, MFMA bf16 + global_load_lds weight-ring (R4).
// 128 persistent blocks x 16 rows, 8 waves. Weights stream L2->LDS ring via
// global_load_lds (8 outstanding 1KB frags/wave, counted vmcnt(4)), then
// ds_read_b128 -> mfma_f32_16x16x32_bf16. Activations in XOR-swizzled bf16 LDS.
// RK4 state in registers. Biases preloaded to LDS (keeps K-loop vmcnt clean).

typedef __attribute__((ext_vector_type(4))) float f32x4;
typedef __attribute__((ext_vector_type(8))) short s16x8;

#define N_AG   2048
#define D_IN   10
#define NPTS   46

#define OFF_W0P 0
#define OFF_W1P (128 * 512)
#define OFF_W2P (OFF_W1P + 512 * 512)
#define OFF_W3P (OFF_W2P + 512 * 512)
#define OFF_END (OFF_W3P + 512 * 1280)   // ushorts

__device__ __forceinline__ ushort f2bf(float v) {
  __hip_bfloat16 h = __float2bfloat16(v);
  return *reinterpret_cast<ushort*>(&h);
}
__device__ __forceinline__ float bf2f(ushort u) {
  union { unsigned u; float f; } c; c.u = ((unsigned)u) << 16; return c.f;
}

// async global->LDS, 16B per lane: lane i reads g(+its own addr), writes ldsbase + i*16
__device__ __forceinline__ void gload_lds16(const void* g, void* l) {
  __builtin_amdgcn_global_load_lds(
      (const __attribute__((address_space(1))) unsigned int*)g,
      (__attribute__((address_space(3))) unsigned int*)l, 16, 0, 0);
}

// Pack W (O x K fp32, row-major) into MFMA B-fragment order (verified R2/R3):
// packed[((ct*KS+ks)*64 + lane)*8 + j] = bf16(W[col][k]),
// col = ct*16 + (lane&15), k = ks*32 + (lane>>4)*8 + j.
__global__ void pack_w(const float* __restrict__ W, ushort* __restrict__ Wp,
                       int O, int K) {
  int idx = blockIdx.x * blockDim.x + threadIdx.x;
  if (idx >= O * K) return;
  int j    = idx & 7;
  int lane = (idx >> 3) & 63;
  int rest = idx >> 9;
  int KS   = K >> 5;
  int ks   = rest % KS;
  int ct   = rest / KS;
  int col  = (ct << 4) + (lane & 15);
  int k    = (ks << 5) + ((lane >> 4) << 3) + j;
  Wp[idx]  = f2bf(W[col * K + k]);
}

// Natural cubic spline derivative table (verified R1-R3).
__global__ void spline_dx_k(const float* __restrict__ x, float* __restrict__ dX) {
  int idx = blockIdx.x * blockDim.x + threadIdx.x;
  if (idx >= N_AG * D_IN) return;
  int n = idx / D_IN;
  int d = idx - n * D_IN;

  float xv[16];
#pragma unroll
  for (int t = 0; t < 16; ++t) xv[t] = x[n * 160 + t * 10 + d];

  float cp[15], dp[15], M[16];
  {
    float rhs = 6.0f * (xv[2] - 2.0f * xv[1] + xv[0]);
    cp[1] = 0.25f;
    dp[1] = rhs * 0.25f;
#pragma unroll
    for (int i = 2; i <= 14; ++i) {
      rhs = 6.0f * (xv[i + 1] - 2.0f * xv[i] + xv[i - 1]);
      float m = 1.0f / (4.0f - cp[i - 1]);
      cp[i] = m;
      dp[i] = (rhs - dp[i - 1]) * m;
    }
    M[0] = 0.0f; M[15] = 0.0f;
    M[14] = dp[14];
#pragma unroll
    for (int i = 13; i >= 1; --i) M[i] = dp[i] - cp[i] * M[i + 1];
  }

#pragma unroll
  for (int p = 0; p < NPTS; ++p) {
    int i; float u;
    if (p < 45) { i = p / 3; u = (float)(p % 3) * (1.0f / 3.0f); }
    else        { i = 14;    u = 1.0f; }
    float b = (xv[i + 1] - xv[i]) - (2.0f * M[i] + M[i + 1]) * (1.0f / 6.0f);
    dX[p * (N_AG * D_IN) + idx] = b + M[i] * u + (M[i + 1] - M[i]) * (u * u * 0.5f);
  }
}

// FC layer via 8-deep fragment ring. Frag batch = 4 frags (2 t-tiles x 2 ks).
// NB batches, 2 in flight; wait vmcnt(4) -> consume 4 frags -> issue batch b+2.
template <int KS, int NT, bool RELU>
__device__ __forceinline__ void fc_ring(const ushort* __restrict__ Ain, int arowb,
                                        const ushort* __restrict__ Wp,
                                        ushort* __restrict__ ring,   // 8 slots x 512 ushorts
                                        const float* __restrict__ bias_lds,
                                        ushort* __restrict__ Outb, int orowb,
                                        int w, int lane) {
  constexpr int NB = (KS * NT) / 4;
  static_assert((NT % 2 == 0) && (KS % 2 == 0) && NB >= 2, "");
  const int row = lane & 15;
  const int g   = lane >> 4;
  const char* abase = (const char*)Ain + row * arowb;
  const int aswz = (row & 7) << 4;

  f32x4 acc[NT];
#pragma unroll
  for (int t = 0; t < NT; ++t) acc[t] = (f32x4){0.f, 0.f, 0.f, 0.f};

#define ISSUE_BATCH(bb)                                                          \
  {                                                                              \
    const int p_ = (bb) / (KS / 2), kb_ = (bb) % (KS / 2);                       \
    const int t0_ = 2 * p_, k0_ = 2 * kb_;                                       \
    ushort* s_ = ring + (((bb) & 1) << 11);                                      \
    const int c0_ = (w + (t0_ << 3)) * KS, c1_ = (w + ((t0_ + 1) << 3)) * KS;    \
    gload_lds16(Wp + (((c0_ + k0_) * 64 + lane) << 3), s_);                      \
    gload_lds16(Wp + (((c1_ + k0_) * 64 + lane) << 3), s_ + 512);                \
    gload_lds16(Wp + (((c0_ + k0_ + 1) * 64 + lane) << 3), s_ + 1024);           \
    gload_lds16(Wp + (((c1_ + k0_ + 1) * 64 + lane) << 3), s_ + 1536);           \
  }

  ISSUE_BATCH(0)
  ISSUE_BATCH(1)

#pragma unroll
  for (int b = 0; b < NB; ++b) {
    const int p = b / (KS / 2), kb = b % (KS / 2);
    const int t0 = 2 * p, k0 = 2 * kb;
    asm volatile("s_waitcnt vmcnt(4)" ::: "memory");
    const ushort* s = ring + ((b & 1) << 11);
    s16x8 a0 = *(const s16x8*)(abase + ((((k0) << 6) + (g << 4)) ^ aswz));
    s16x8 a1 = *(const s16x8*)(abase + ((((k0 + 1) << 6) + (g << 4)) ^ aswz));
    s16x8 b00 = *(const s16x8*)(s + lane * 8);
    s16x8 b10 = *(const s16x8*)(s + 512 + lane * 8);
    s16x8 b01 = *(const s16x8*)(s + 1024 + lane * 8);
    s16x8 b11 = *(const s16x8*)(s + 1536 + lane * 8);
    acc[t0]     = __builtin_amdgcn_mfma_f32_16x16x32_bf16(a0, b00, acc[t0], 0, 0, 0);
    acc[t0 + 1] = __builtin_amdgcn_mfma_f32_16x16x32_bf16(a0, b10, acc[t0 + 1], 0, 0, 0);
    acc[t0]     = __builtin_amdgcn_mfma_f32_16x16x32_bf16(a1, b01, acc[t0], 0, 0, 0);
    acc[t0 + 1] = __builtin_amdgcn_mfma_f32_16x16x32_bf16(a1, b11, acc[t0 + 1], 0, 0, 0);
    if (b + 2 < NB) ISSUE_BATCH(b + 2)
  }
#undef ISSUE_BATCH

#pragma unroll
  for (int t = 0; t < NT; ++t) {
    int ct  = w + (t << 3);
    int col = (ct << 4) + row;
    float bb = bias_lds[col];
#pragma unroll
    for (int r = 0; r < 4; ++r) {
      int orow = (g << 2) + r;
      float v = acc[t][r] + bb;
      if (RELU) v = fmaxf(v, 0.f);
      else      v = 1.0f - 2.0f * __builtin_amdgcn_rcpf(__expf(2.0f * v) + 1.0f);
      int byte = (orow * orowb + (col << 1)) ^ ((orow & 7) << 4);
      *(ushort*)((char*)Outb + byte) = f2bf(v);
    }
  }
}

__global__ __launch_bounds__(512, 2) void cde_mfma(
    const float* __restrict__ x, const int* __restrict__ mask,
    const float* __restrict__ We, const float* __restrict__ be,
    const float* __restrict__ b0, const float* __restrict__ b1,
    const float* __restrict__ b2, const float* __restrict__ b3,
    const ushort* __restrict__ Wp, const float* __restrict__ dX,
    float* __restrict__ out) {
  const int tid  = threadIdx.x;
  const int lane = tid & 63;
  const int w    = tid >> 6;
  const int n0   = blockIdx.x << 4;

  __shared__ ushort A0[16 * 128];
  __shared__ ushort H1[16 * 512];
  __shared__ ushort H2[16 * 512];
  __shared__ ushort G[16 * 1280];
  __shared__ ushort WRING[8][8][512];   // [wave][slot][frag 64 lanes x 16B]
  __shared__ float  BL[2816];           // b0|b1|b2|b3
  __shared__ float  dXs[16][10];

  float zreg[4], k1r[4], k2r[4], k3r[4];

  // biases -> LDS (once)
  {
    int i = tid;
    BL[i] = b0[i]; BL[512 + i] = b1[i]; BL[1024 + i] = b2[i];
    BL[1536 + i] = b3[i];
    if (i + 512 < 1280) BL[2048 + i] = b3[i + 512];
    if (tid < 256) BL[1536 + 1024 + tid] = b3[1024 + tid];
  }

  // z0 = x[:,0,:] @ We^T + be
#pragma unroll
  for (int q = 0; q < 4; ++q) {
    int idx = (q << 9) + tid;
    int e = idx & 127, row = idx >> 7;
    float acc = be[e];
    const float* xr = x + (n0 + row) * 160;
#pragma unroll
    for (int d = 0; d < 10; ++d) acc = fmaf(xr[d], We[e * 10 + d], acc);
    zreg[q] = acc;
    int byte = ((row << 8) + (e << 1)) ^ ((row & 7) << 4);
    *(ushort*)((char*)A0 + byte) = f2bf(acc);
  }
  __syncthreads();

  ushort* myring = &WRING[w][0][0];

#pragma unroll 1
  for (int s = 0; s < 15; ++s) {
#pragma unroll 1
    for (int st = 0; st < 4; ++st) {
      if (tid < 160) {
        int p = (st < 3) ? (3 * s + st) : ((s < 14) ? (3 * s + 3) : 45);
        dXs[tid / 10][tid % 10] = dX[p * (N_AG * D_IN) + n0 * 10 + tid];
      }
      fc_ring<4, 4, true>(A0, 256, Wp + OFF_W0P, myring, BL, H1, 1024, w, lane);
      __syncthreads();
      fc_ring<16, 4, true>(H1, 1024, Wp + OFF_W1P, myring, BL + 512, H2, 1024, w, lane);
      __syncthreads();
      fc_ring<16, 4, true>(H2, 1024, Wp + OFF_W2P, myring, BL + 1024, H1, 1024, w, lane);
      __syncthreads();
      fc_ring<16, 10, false>(H1, 1024, Wp + OFF_W3P, myring, BL + 1536, G, 2560, w, lane);
      __syncthreads();

      // vf + RK4 (3/8 rule), state in registers
#pragma unroll
      for (int q = 0; q < 4; ++q) {
        int idx = (q << 9) + tid;
        int e = idx & 127, row = idx >> 7;
        float dv = 0.f;
#pragma unroll
        for (int d = 0; d < 10; ++d) {
          int byte = (row * 2560 + ((e * 10 + d) << 1)) ^ ((row & 7) << 4);
          dv = fmaf(bf2f(*(const ushort*)((const char*)G + byte)), dXs[row][d], dv);
        }
        float z = zreg[q], zin;
        if (st == 0)      { k1r[q] = dv; zin = z + dv * (1.f / 3.f); }
        else if (st == 1) { k2r[q] = dv; zin = z + dv - k1r[q] * (1.f / 3.f); }
        else if (st == 2) { k3r[q] = dv; zin = z + k1r[q] - k2r[q] + dv; }
        else {
          z += (k1r[q] + 3.f * (k2r[q] + k3r[q]) + dv) * 0.125f;
          zreg[q] = z; zin = z;
        }
        int byte = ((row << 8) + (e << 1)) ^ ((row & 7) << 4);
        *(ushort*)((char*)A0 + byte) = f2bf(zin);
      }
      __syncthreads();
    }
  }

#pragma unroll
  for (int q = 0; q < 4; ++q) {
    int idx = (q << 9) + tid;
    int e = idx & 127, row = idx >> 7;
    out[(n0 + row) * 128 + e] = (mask[n0 + row] != 0) ? zreg[q] : 0.f;
  }
}

extern "C" void kernel_launch(void* const* d_in, const int* in_sizes, int n_in,
                              void* d_out, int out_size, void* d_ws, size_t ws_size,
                              hipStream_t stream) {
  const float* x    = (const float*)d_in[1];
  const int*   mask = (const int*)d_in[2];
  const float* We   = (const float*)d_in[3];
  const float* be   = (const float*)d_in[4];
  const float* W0   = (const float*)d_in[5];
  const float* b0   = (const float*)d_in[6];
  const float* W1   = (const float*)d_in[7];
  const float* b1   = (const float*)d_in[8];
  const float* W2   = (const float*)d_in[9];
  const float* b2   = (const float*)d_in[10];
  const float* W3   = (const float*)d_in[11];
  const float* b3   = (const float*)d_in[12];
  float* out = (float*)d_out;

  ushort* wp = (ushort*)d_ws;
  float*  dX = (float*)((char*)d_ws + (size_t)OFF_END * 2);

  pack_w<<<(128 * 512 + 255) / 256, 256, 0, stream>>>(W0, wp + OFF_W0P, 512, 128);
  pack_w<<<(512 * 512 + 255) / 256, 256, 0, stream>>>(W1, wp + OFF_W1P, 512, 512);
  pack_w<<<(512 * 512 + 255) / 256, 256, 0, stream>>>(W2, wp + OFF_W2P, 512, 512);
  pack_w<<<(512 * 1280 + 255) / 256, 256, 0, stream>>>(W3, wp + OFF_W3P, 1280, 512);
  spline_dx_k<<<(N_AG * D_IN + 255) / 256, 256, 0, stream>>>(x, dX);
  cde_mfma<<<128, 512, 0, stream>>>(x, mask, We, be, b0, b1, b2, b3, wp, dX, out);
}

// Round 5
// 2430.404 us; speedup vs baseline: 2.7802x; 2.7802x over previous
//
#include <hip/hip_runtime.h>
#include <hip/hip_bf16.h>

// Neural CDE forward, R5: full-machine, spill-free, fused vf-contraction.
// 256 persistent blocks x 8 rows, 8 waves, 1 block/CU on all 256 CUs.
// Layers via mfma_f32_16x16x32_bf16 with dup-row A (row = lane&7): C rows 8..15
// duplicate 0..7 and are skipped in the epilogue. B-fragments loaded to VGPRs
// straight from L2 (coalesced 1KB/instr), unroll 2, NT<=5 -> fits 128 VGPRs.
// L3 epilogue fuses tanh + D-contraction via LDS atomicAdd into vf[8][128]
// (no G buffer). RK4 (3/8) state in registers.

typedef __attribute__((ext_vector_type(4))) float f32x4;
typedef __attribute__((ext_vector_type(8))) short s16x8;

#define N_AG  2048
#define D_IN  10
#define NPTS  46
#define RROWS 8

#define OFF_W0P 0
#define OFF_W1P (128 * 512)
#define OFF_W2P (OFF_W1P + 512 * 512)
#define OFF_W3P (OFF_W2P + 512 * 512)
#define OFF_END (OFF_W3P + 512 * 1280)   // ushorts

__device__ __forceinline__ ushort f2bf(float v) {
  __hip_bfloat16 h = __float2bfloat16(v);
  return *reinterpret_cast<ushort*>(&h);
}

// Pack W (O x K fp32, row-major) into MFMA B-fragment order (verified R2-R4):
// packed[((ct*KS+ks)*64 + lane)*8 + j] = bf16(W[col][k]),
// col = ct*16 + (lane&15), k = ks*32 + (lane>>4)*8 + j.
__global__ void pack_w(const float* __restrict__ W, ushort* __restrict__ Wp,
                       int O, int K) {
  int idx = blockIdx.x * blockDim.x + threadIdx.x;
  if (idx >= O * K) return;
  int j    = idx & 7;
  int lane = (idx >> 3) & 63;
  int rest = idx >> 9;
  int KS   = K >> 5;
  int ks   = rest % KS;
  int ct   = rest / KS;
  int col  = (ct << 4) + (lane & 15);
  int k    = (ks << 5) + ((lane >> 4) << 3) + j;
  Wp[idx]  = f2bf(W[col * K + k]);
}

// Natural cubic spline derivative table (verified R1-R4).
__global__ void spline_dx_k(const float* __restrict__ x, float* __restrict__ dX) {
  int idx = blockIdx.x * blockDim.x + threadIdx.x;
  if (idx >= N_AG * D_IN) return;
  int n = idx / D_IN;
  int d = idx - n * D_IN;

  float xv[16];
#pragma unroll
  for (int t = 0; t < 16; ++t) xv[t] = x[n * 160 + t * 10 + d];

  float cp[15], dp[15], M[16];
  {
    float rhs = 6.0f * (xv[2] - 2.0f * xv[1] + xv[0]);
    cp[1] = 0.25f;
    dp[1] = rhs * 0.25f;
#pragma unroll
    for (int i = 2; i <= 14; ++i) {
      rhs = 6.0f * (xv[i + 1] - 2.0f * xv[i] + xv[i - 1]);
      float m = 1.0f / (4.0f - cp[i - 1]);
      cp[i] = m;
      dp[i] = (rhs - dp[i - 1]) * m;
    }
    M[0] = 0.0f; M[15] = 0.0f;
    M[14] = dp[14];
#pragma unroll
    for (int i = 13; i >= 1; --i) M[i] = dp[i] - cp[i] * M[i + 1];
  }

#pragma unroll
  for (int p = 0; p < NPTS; ++p) {
    int i; float u;
    if (p < 45) { i = p / 3; u = (float)(p % 3) * (1.0f / 3.0f); }
    else        { i = 14;    u = 1.0f; }
    float b = (xv[i + 1] - xv[i]) - (2.0f * M[i] + M[i + 1]) * (1.0f / 6.0f);
    dX[p * (N_AG * D_IN) + idx] = b + M[i] * u + (M[i + 1] - M[i]) * (u * u * 0.5f);
  }
}

// One FC slice: rows 0..7 x (KS*32) @ W-tile columns ct = w + (tbase+t)*8.
// VF=false: relu -> swizzled bf16 store into Outb.
// VF=true : tanh -> vf[orow][col/10] += v * dXs[orow][col%10] (LDS atomic).
template <int KS, int NT, bool VF>
__device__ __forceinline__ void fc(const ushort* __restrict__ Ain, int arowb,
                                   const ushort* __restrict__ Wp,
                                   const float* __restrict__ bias_lds,
                                   ushort* __restrict__ Outb, int orowb,
                                   float (*__restrict__ vf)[128],
                                   const float (*__restrict__ dXs)[D_IN],
                                   int w, int lane, int tbase) {
  f32x4 acc[NT];
#pragma unroll
  for (int t = 0; t < NT; ++t) acc[t] = (f32x4){0.f, 0.f, 0.f, 0.f};

  const int row8 = lane & 7;
  const int g    = lane >> 4;
  const char* abase = (const char*)Ain + row8 * arowb;
  const int aswz = row8 << 4;

#pragma unroll 2
  for (int ks = 0; ks < KS; ++ks) {
    s16x8 a = *(const s16x8*)(abase + (((ks << 6) + (g << 4)) ^ aswz));
#pragma unroll
    for (int t = 0; t < NT; ++t) {
      int ct = w + ((tbase + t) << 3);
      s16x8 b = *(const s16x8*)(Wp + (((ct * KS + ks) * 64 + lane) << 3));
      acc[t] = __builtin_amdgcn_mfma_f32_16x16x32_bf16(a, b, acc[t], 0, 0, 0);
    }
  }

#pragma unroll
  for (int t = 0; t < NT; ++t) {
    int ct  = w + ((tbase + t) << 3);
    int col = (ct << 4) + (lane & 15);
    float bb = bias_lds[col];
#pragma unroll
    for (int r = 0; r < 4; ++r) {
      int orow = (g << 2) + r;
      if (orow < RROWS) {              // rows 8..15 are dup of 0..7: skip
        float v = acc[t][r] + bb;
        if (!VF) {
          v = fmaxf(v, 0.f);
          int byte = (orow * orowb + (col << 1)) ^ (orow << 4);
          *(ushort*)((char*)Outb + byte) = f2bf(v);
        } else {
          v = 1.0f - 2.0f * __builtin_amdgcn_rcpf(__expf(2.0f * v) + 1.0f);
          int e = col / 10, d = col - e * 10;
          atomicAdd(&vf[orow][e], v * dXs[orow][d]);
        }
      }
    }
  }
}

__global__ __launch_bounds__(512, 2) void cde_mfma(
    const float* __restrict__ x, const int* __restrict__ mask,
    const float* __restrict__ We, const float* __restrict__ be,
    const float* __restrict__ b0, const float* __restrict__ b1,
    const float* __restrict__ b2, const float* __restrict__ b3,
    const ushort* __restrict__ Wp, const float* __restrict__ dX,
    float* __restrict__ out) {
  const int tid  = threadIdx.x;
  const int lane = tid & 63;
  const int w    = tid >> 6;
  const int n0   = blockIdx.x * RROWS;

  __shared__ ushort A0[RROWS * 128];   // 2 KB, swizzled bf16
  __shared__ ushort H1[RROWS * 512];   // 8 KB
  __shared__ ushort H2[RROWS * 512];   // 8 KB
  __shared__ float  BL[2816];          // b0|b1|b2|b3
  __shared__ float  vf[RROWS][128];    // fused contraction accumulator
  __shared__ float  dXs[RROWS][D_IN];

  float zreg[2], k1r[2], k2r[2], k3r[2];

  // biases -> LDS (once)
  {
    int i = tid;
    BL[i] = b0[i]; BL[512 + i] = b1[i]; BL[1024 + i] = b2[i];
    BL[1536 + i] = b3[i];
    BL[2048 + i] = b3[512 + i];
    if (tid < 256) BL[2560 + tid] = b3[1024 + tid];
  }

  // z0 = x[:,0,:] @ We^T + be   (2 (row,e) elements per thread)
#pragma unroll
  for (int q = 0; q < 2; ++q) {
    int idx = (q << 9) + tid;
    int e = idx & 127, row = idx >> 7;
    float acc = be[e];
    const float* xr = x + (n0 + row) * 160;
#pragma unroll
    for (int d = 0; d < 10; ++d) acc = fmaf(xr[d], We[e * 10 + d], acc);
    zreg[q] = acc;
    int byte = ((row << 8) + (e << 1)) ^ (row << 4);
    *(ushort*)((char*)A0 + byte) = f2bf(acc);
  }
  __syncthreads();

#pragma unroll 1
  for (int s = 0; s < 15; ++s) {
#pragma unroll 1
    for (int st = 0; st < 4; ++st) {
      if (tid < RROWS * D_IN) {
        int p = (st < 3) ? (3 * s + st) : ((s < 14) ? (3 * s + 3) : 45);
        dXs[tid / 10][tid % 10] = dX[p * (N_AG * D_IN) + n0 * 10 + tid];
      }
      fc<4, 2, false>(A0, 256, Wp + OFF_W0P, BL, H1, 1024, vf, dXs, w, lane, 0);
      fc<4, 2, false>(A0, 256, Wp + OFF_W0P, BL, H1, 1024, vf, dXs, w, lane, 2);
      __syncthreads();
      fc<16, 2, false>(H1, 1024, Wp + OFF_W1P, BL + 512, H2, 1024, vf, dXs, w, lane, 0);
      fc<16, 2, false>(H1, 1024, Wp + OFF_W1P, BL + 512, H2, 1024, vf, dXs, w, lane, 2);
      __syncthreads();
      fc<16, 2, false>(H2, 1024, Wp + OFF_W2P, BL + 1024, H1, 1024, vf, dXs, w, lane, 0);
      fc<16, 2, false>(H2, 1024, Wp + OFF_W2P, BL + 1024, H1, 1024, vf, dXs, w, lane, 2);
      // zero vf for this stage's contraction (disjoint; synced below)
      ((float*)vf)[tid] = 0.f;
      ((float*)vf)[512 + tid] = 0.f;
      __syncthreads();
      fc<16, 5, true>(H1, 1024, Wp + OFF_W3P, BL + 1536, nullptr, 0, vf, dXs, w, lane, 0);
      fc<16, 5, true>(H1, 1024, Wp + OFF_W3P, BL + 1536, nullptr, 0, vf, dXs, w, lane, 5);
      __syncthreads();

      // RK4 (3/8 rule), state in registers
#pragma unroll
      for (int q = 0; q < 2; ++q) {
        int idx = (q << 9) + tid;
        int e = idx & 127, row = idx >> 7;
        float dv = vf[row][e];
        float z = zreg[q], zin;
        if (st == 0)      { k1r[q] = dv; zin = z + dv * (1.f / 3.f); }
        else if (st == 1) { k2r[q] = dv; zin = z + dv - k1r[q] * (1.f / 3.f); }
        else if (st == 2) { k3r[q] = dv; zin = z + k1r[q] - k2r[q] + dv; }
        else {
          z += (k1r[q] + 3.f * (k2r[q] + k3r[q]) + dv) * 0.125f;
          zreg[q] = z; zin = z;
        }
        int byte = ((row << 8) + (e << 1)) ^ (row << 4);
        *(ushort*)((char*)A0 + byte) = f2bf(zin);
      }
      __syncthreads();
    }
  }

#pragma unroll
  for (int q = 0; q < 2; ++q) {
    int idx = (q << 9) + tid;
    int e = idx & 127, row = idx >> 7;
    out[(n0 + row) * 128 + e] = (mask[n0 + row] != 0) ? zreg[q] : 0.f;
  }
}

extern "C" void kernel_launch(void* const* d_in, const int* in_sizes, int n_in,
                              void* d_out, int out_size, void* d_ws, size_t ws_size,
                              hipStream_t stream) {
  const float* x    = (const float*)d_in[1];
  const int*   mask = (const int*)d_in[2];
  const float* We   = (const float*)d_in[3];
  const float* be   = (const float*)d_in[4];
  const float* W0   = (const float*)d_in[5];
  const float* b0   = (const float*)d_in[6];
  const float* W1   = (const float*)d_in[7];
  const float* b1   = (const float*)d_in[8];
  const float* W2   = (const float*)d_in[9];
  const float* b2   = (const float*)d_in[10];
  const float* W3   = (const float*)d_in[11];
  const float* b3   = (const float*)d_in[12];
  float* out = (float*)d_out;

  ushort* wp = (ushort*)d_ws;
  float*  dX = (float*)((char*)d_ws + (size_t)OFF_END * 2);

  pack_w<<<(128 * 512 + 255) / 256, 256, 0, stream>>>(W0, wp + OFF_W0P, 512, 128);
  pack_w<<<(512 * 512 + 255) / 256, 256, 0, stream>>>(W1, wp + OFF_W1P, 512, 512);
  pack_w<<<(512 * 512 + 255) / 256, 256, 0, stream>>>(W2, wp + OFF_W2P, 512, 512);
  pack_w<<<(512 * 1280 + 255) / 256, 256, 0, stream>>>(W3, wp + OFF_W3P, 1280, 512);
  spline_dx_k<<<(N_AG * D_IN + 255) / 256, 256, 0, stream>>>(x, dX);
  cde_mfma<<<256, 512, 0, stream>>>(x, mask, We, be, b0, b1, b2, b3, wp, dX, out);
}